// Round 3
// baseline (702.771 us; speedup 1.0000x reference)
//
#include <hip/hip_runtime.h>

// Problem: y[b,o] = sum_i x[b,i]*W[i,o]*w_mask[b,i,o] + bias[o]*b_mask[b,o]
// B=32, IN_F=1024, OUT_F=4096. f32 tensors, int32 masks.
//
// Round-2 post-mortem: scalar-dword version ran 0.79 TB/s (12% peak) — the
// compiler kept ~1-2 loads in flight per wave (Little's law back-solve from
// measured BW). Fix: (a) int4/float4 loads = 1 KiB/wave-instr, (b) K-split
// into 16 chunks -> 2048 blocks (4-8 blk/CU vs 2) + 8 MiB partials in d_ws,
// (c) bid = b*64 + slice keeps weight-slice sharers on one XCD (64%8==0).

#define B_DIM 32
#define IN_F 1024
#define OUT_F 4096
#define N_CHUNK 16
#define I_CHUNK (IN_F / N_CHUNK)      // 64 rows of the dot product per block
#define O_PER_BLK 1024                // 256 threads x 4 outputs
#define BO (B_DIM * OUT_F)            // 131072

// partial[chunk][b][o] : 16 x 32 x 4096 f32 = 8 MiB in d_ws
__global__ __launch_bounds__(256, 4) void masked_gemv_partial(
    const float* __restrict__ x,       // [B, IN_F]
    const float* __restrict__ weight,  // [IN_F, OUT_F]
    const int* __restrict__ w_mask,    // [B, IN_F, OUT_F]
    float* __restrict__ partial)
{
    const int bid   = blockIdx.x;        // b*64 + (o_blk*16 + chunk)
    const int b     = bid >> 6;
    const int s     = bid & 63;
    const int o_blk = s >> 4;
    const int chunk = s & 15;
    const int i0    = chunk * I_CHUNK;
    const int o     = o_blk * O_PER_BLK + (threadIdx.x << 2);

    // Stage the 64 x-values this block needs (256 B of LDS).
    __shared__ float xs[I_CHUNK];
    if (threadIdx.x < I_CHUNK) xs[threadIdx.x] = x[b * IN_F + i0 + threadIdx.x];
    __syncthreads();

    const int*   mptr = w_mask + (size_t)b * IN_F * OUT_F + (size_t)i0 * OUT_F + o;
    const float* wptr = weight + (size_t)i0 * OUT_F + o;

    float4 acc = {0.f, 0.f, 0.f, 0.f};
#pragma unroll 8
    for (int i = 0; i < I_CHUNK; ++i) {
        const float xi = xs[i];  // wave-uniform -> LDS broadcast
        const int4   m = *(const int4*)  (mptr + (size_t)i * OUT_F);
        const float4 w = *(const float4*)(wptr + (size_t)i * OUT_F);
        acc.x = fmaf(xi * (float)m.x, w.x, acc.x);
        acc.y = fmaf(xi * (float)m.y, w.y, acc.y);
        acc.z = fmaf(xi * (float)m.z, w.z, acc.z);
        acc.w = fmaf(xi * (float)m.w, w.w, acc.w);
    }

    *(float4*)(partial + (size_t)chunk * BO + b * OUT_F + o) = acc;
}

__global__ __launch_bounds__(256) void reduce_bias_kernel(
    const float* __restrict__ partial,  // [N_CHUNK][B][OUT_F]
    const float* __restrict__ bias,     // [OUT_F]
    const int* __restrict__ b_mask,     // [B, OUT_F]
    float* __restrict__ out)            // [B, OUT_F]
{
    const int tid = blockIdx.x * 256 + threadIdx.x;  // [0, BO)
    float s = 0.f;
#pragma unroll
    for (int c = 0; c < N_CHUNK; ++c)
        s += partial[(size_t)c * BO + tid];
    const int o = tid & (OUT_F - 1);
    out[tid] = fmaf(bias[o], (float)b_mask[tid], s);
}

extern "C" void kernel_launch(void* const* d_in, const int* in_sizes, int n_in,
                              void* d_out, int out_size, void* d_ws, size_t ws_size,
                              hipStream_t stream) {
    const float* x      = (const float*)d_in[0];
    const float* weight = (const float*)d_in[1];
    const float* bias   = (const float*)d_in[2];
    const int*   w_mask = (const int*)d_in[3];
    const int*   b_mask = (const int*)d_in[4];
    float* out     = (float*)d_out;
    float* partial = (float*)d_ws;  // 8 MiB needed; re-written fully every call

    masked_gemv_partial<<<B_DIM * 64, 256, 0, stream>>>(x, weight, w_mask, partial);
    reduce_bias_kernel<<<BO / 256, 256, 0, stream>>>(partial, bias, b_mask, out);
}

// Round 4
// 676.513 us; speedup vs baseline: 1.0388x; 1.0388x over previous
//
#include <hip/hip_runtime.h>

// y[b,o] = sum_i x[b,i]*W[i,o]*w_mask[b,i,o] + bias[o]*b_mask[b,o]
// B=32, IN_F=1024, OUT_F=4096. f32 tensors, int32 masks.
//
// Round-3 post-mortem: top-5 (sorted by dur_us) are all 2 GiB harness poison
// fills (333 us each) and our kernels are absent (<335 us) => dur_us includes
// ~520 us of fixed harness restore/poison; kernel share ~160 us vs 90 us HBM
// floor (mask 512 MiB read-once + weight 16 MiB).
//
// This round: nontemporal mask loads (read-once; protect weight L2 residency),
// N_CHUNK=4 -> 512 blocks (2/CU, all co-resident; weight-slice sharers on one
// XCD since bid=b*16+s, 16%8==0), partials 2 MiB nt-stored in d_ws.

#define B_DIM 32
#define IN_F 1024
#define OUT_F 4096
#define N_CHUNK 4
#define I_CHUNK (IN_F / N_CHUNK)   // 256 i-rows per block
#define BO (B_DIM * OUT_F)         // 131072

typedef int   v4i __attribute__((ext_vector_type(4)));
typedef float v4f __attribute__((ext_vector_type(4)));

// partial[chunk][b][o] : 4 x 32 x 4096 f32 = 2 MiB in d_ws
__global__ __launch_bounds__(256, 2) void masked_gemv_partial(
    const float* __restrict__ x,       // [B, IN_F]
    const float* __restrict__ weight,  // [IN_F, OUT_F]
    const int* __restrict__ w_mask,    // [B, IN_F, OUT_F]
    float* __restrict__ partial)
{
    const int bid   = blockIdx.x;      // b*16 + o_blk*4 + chunk
    const int b     = bid >> 4;
    const int s     = bid & 15;
    const int o_blk = s >> 2;
    const int chunk = s & 3;
    const int i0    = chunk * I_CHUNK;
    const int o     = o_blk * 1024 + (threadIdx.x << 2);

    __shared__ float xs[I_CHUNK];      // 1 KiB
    xs[threadIdx.x] = x[b * IN_F + i0 + threadIdx.x];
    __syncthreads();

    const int*   mptr = w_mask + (size_t)b * IN_F * OUT_F + (size_t)i0 * OUT_F + o;
    const float* wptr = weight + (size_t)i0 * OUT_F + o;

    v4f acc = {0.f, 0.f, 0.f, 0.f};
#pragma unroll 8
    for (int i = 0; i < I_CHUNK; ++i) {
        const float xi = xs[i];  // wave-uniform -> LDS broadcast
        const v4i m = __builtin_nontemporal_load((const v4i*)(mptr + (size_t)i * OUT_F));
        const v4f w = *(const v4f*)(wptr + (size_t)i * OUT_F);
        acc.x = fmaf(xi * (float)m.x, w.x, acc.x);
        acc.y = fmaf(xi * (float)m.y, w.y, acc.y);
        acc.z = fmaf(xi * (float)m.z, w.z, acc.z);
        acc.w = fmaf(xi * (float)m.w, w.w, acc.w);
    }

    __builtin_nontemporal_store(acc,
        (v4f*)(partial + (size_t)chunk * BO + b * OUT_F + o));
}

__global__ __launch_bounds__(256) void reduce_bias_kernel(
    const float* __restrict__ partial,  // [N_CHUNK][B][OUT_F]
    const float* __restrict__ bias,     // [OUT_F]
    const int* __restrict__ b_mask,     // [B, OUT_F]
    float* __restrict__ out)            // [B, OUT_F]
{
    const int tid = blockIdx.x * 256 + threadIdx.x;  // [0, BO)
    float s0 = partial[tid]               + partial[(size_t)1 * BO + tid];
    float s1 = partial[(size_t)2 * BO + tid] + partial[(size_t)3 * BO + tid];
    const int o = tid & (OUT_F - 1);
    out[tid] = fmaf(bias[o], (float)b_mask[tid], s0 + s1);
}

extern "C" void kernel_launch(void* const* d_in, const int* in_sizes, int n_in,
                              void* d_out, int out_size, void* d_ws, size_t ws_size,
                              hipStream_t stream) {
    const float* x      = (const float*)d_in[0];
    const float* weight = (const float*)d_in[1];
    const float* bias   = (const float*)d_in[2];
    const int*   w_mask = (const int*)d_in[3];
    const int*   b_mask = (const int*)d_in[4];
    float* out     = (float*)d_out;
    float* partial = (float*)d_ws;  // 2 MiB used

    masked_gemv_partial<<<B_DIM * 16, 256, 0, stream>>>(x, weight, w_mask, partial);
    reduce_bias_kernel<<<BO / 256, 256, 0, stream>>>(partial, bias, b_mask, out);
}